// Round 3
// baseline (336.563 us; speedup 1.0000x reference)
//
#include <hip/hip_runtime.h>

// WarpLayer: bilinear backward warp.
// image [B,H,W,C] f32, flow [B,H,W,2] f32 -> out [B,H,W,C] f32
// q = grid - flow; y0 = clip(floor(qy),0,H-2); alpha = clip(q - floor_clipped, 0, 1)
//
// Layout: C=32 innermost => corner pixel = 128 contiguous bytes. 8 threads per
// pixel (one float4 channel-group each); a 64-lane wave covers 8 pixels, so each
// corner gather instruction touches 8 aligned 128B segments (segment-coalesced),
// and the output store is perfectly coalesced.
//
// R3 = R2 with the nontemporal builtins applied to clang native vectors
// (ext_vector_type) instead of HIP_vector_type, which the builtin rejects.

#define WB 8
#define WH 384
#define WW 512

typedef float f32x2 __attribute__((ext_vector_type(2)));
typedef float f32x4 __attribute__((ext_vector_type(4)));

__global__ __launch_bounds__(256) void warp_kernel(
    const float* __restrict__ image,
    const float* __restrict__ flow,
    float* __restrict__ out)
{
    const unsigned tid = blockIdx.x * blockDim.x + threadIdx.x;
    const unsigned cg  = tid & 7u;   // float4 group within the 32 channels
    const unsigned pix = tid >> 3;   // linear pixel index b*H*W + h*W + w

    const unsigned w  = pix & (WW - 1);   // W = 512 (pow2)
    const unsigned bh = pix >> 9;         // b*H + h
    const unsigned h  = bh % WH;

    // flow[..,0] = dy, flow[..,1] = dx ; q = grid - flow
    const f32x2 f = __builtin_nontemporal_load(&((const f32x2*)flow)[pix]);
    const float qy = (float)h - f.x;
    const float qx = (float)w - f.y;

    const float fly = fminf(fmaxf(floorf(qy), 0.0f), (float)(WH - 2));
    const float flx = fminf(fmaxf(floorf(qx), 0.0f), (float)(WW - 2));
    const int y0 = (int)fly;
    const int x0 = (int)flx;
    const float ay = fminf(fmaxf(qy - fly, 0.0f), 1.0f);
    const float ax = fminf(fmaxf(qx - flx, 0.0f), 1.0f);

    // 32-bit float4-unit index: pixel (b, y0, x0) = (bh + (y0 - h))*W + x0
    const f32x4* __restrict__ img4 = (const f32x4*)image;
    const unsigned base =
        (((unsigned)((int)bh + (y0 - (int)h)) << 9) + (unsigned)x0) * 8u + cg;

    const f32x4 tl = img4[base];
    const f32x4 tr = img4[base + 8u];            // x0+1
    const f32x4 bl = img4[base + (WW * 8u)];     // y0+1
    const f32x4 br = img4[base + (WW * 8u + 8u)];

    const f32x4 top = ax * (tr - tl) + tl;
    const f32x4 bot = ax * (br - bl) + bl;
    const f32x4 r   = ay * (bot - top) + top;

    __builtin_nontemporal_store(r, &((f32x4*)out)[pix * 8u + cg]);
}

extern "C" void kernel_launch(void* const* d_in, const int* in_sizes, int n_in,
                              void* d_out, int out_size, void* d_ws, size_t ws_size,
                              hipStream_t stream)
{
    const float* image = (const float*)d_in[0];
    const float* flow  = (const float*)d_in[1];
    float* out = (float*)d_out;

    const int nthreads = WB * WH * WW * 8; // 12,582,912 (divisible by 256)
    const int block = 256;
    const int grid = nthreads / block;
    warp_kernel<<<grid, block, 0, stream>>>(image, flow, out);
}